// Round 12
// baseline (196.682 us; speedup 1.0000x reference)
//
#include <hip/hip_runtime.h>
#include <hip/hip_bf16.h>

#define B_TOTAL 2048
#define H 128
#define NL 64
#define NPAIRS 512
#define BPB 4
#define NBLOCKS (B_TOTAL / BPB)   // 512

typedef __attribute__((ext_vector_type(8))) short bf16x8;  // MFMA A/B frag (8 bf16)
typedef __attribute__((ext_vector_type(4))) float f32x4;   // MFMA C/D frag

static __device__ __forceinline__ ushort f2bf(float f) {
    uint u = __float_as_uint(f);
    u += 0x7fffu + ((u >> 16) & 1u);   // RNE
    return (ushort)(u >> 16);
}
static __device__ __forceinline__ uint pk2bf(float x, float y) {
    return (uint)f2bf(x) | ((uint)f2bf(y) << 16);
}

// ---------------------------------------------------------------------------
// edge v6 = v5 + runtime `reps` loop (host passes 2) for MEASUREMENT:
// the dispatch runs the identical 4-batch pipeline `reps` times so either
// (H1) its duration exceeds the 81us harness fills and its counters become
// visible in the top-5, or (H2) dur_us - 187 bounds the edge duration.
// All reps compute identical values; partials written once.
// LDS swizzle: physical_byte = row*256 + (logical_col_byte ^ ((row&15)<<4)).
// ---------------------------------------------------------------------------
__global__ __launch_bounds__(256, 2)
void edge_loss_v6(const float* __restrict__ P,
                  const float* __restrict__ Dsrc,
                  const int* __restrict__ pairs,
                  float* __restrict__ partials,
                  int reps) {
    __shared__ __align__(16) char lds_raw[49152];   // Ab0 | Ab1 | Ub  (16KB each)
    ushort* Ab0  = (ushort*)lds_raw;
    ushort* Ab1  = (ushort*)(lds_raw + 16384);
    ushort* Ub   = (ushort*)(lds_raw + 32768);
    int*    Sint = (int*)(lds_raw + 32768);         // aliases Ub (pre-U only)
    __shared__ float wsum[4];

    const int tid  = threadIdx.x;
    const int lane = tid & 63;
    const int w    = tid >> 6;            // wave 0..3
    const int l15  = lane & 15;
    const int lg   = lane >> 4;           // 0..3
    const uint rmask = (uint)l15 << 4;    // frag rows are tile*16+l15 -> row&15==l15
    const int b0   = blockIdx.x * BPB;

    float4 pf[8];
    auto loadA = [&](int b) {
        const float4* s = reinterpret_cast<const float4*>(P + (size_t)b * H * H);
#pragma unroll
        for (int k = 0; k < 8; ++k) pf[k] = s[tid + k * 256];
    };
    auto cvtStore = [&](ushort* dst) {
#pragma unroll
        for (int k = 0; k < 8; ++k) {
            const int  f4 = tid + k * 256;
            const int  i  = f4 >> 5;                // A row 0..63
            const uint cb = (uint)(f4 & 31) * 8;    // col byte 0..248
            uint2 d2;
            d2.x = pk2bf(pf[k].x, pf[k].y);
            d2.y = pk2bf(pf[k].z, pf[k].w);
            *reinterpret_cast<uint2*>((char*)dst + i * 256 + (cb ^ ((uint)(i & 15) << 4))) = d2;
        }
    };

    // ---- issue first batch's HBM loads immediately (hides under D/S setup) ----
    loadA(b0);

    // ---- D frags -> registers (f32 global, cvt in reg); wave w: rows [32w,32w+32) ----
    bf16x8 dreg[2][4];
#pragma unroll
    for (int c2 = 0; c2 < 2; ++c2) {
        const int drow = (2 * w + c2) * 16 + l15;
#pragma unroll
        for (int ks = 0; ks < 4; ++ks) {
            const float* dp = Dsrc + (size_t)drow * H + ks * 32 + lg * 8;
            float4 x = *reinterpret_cast<const float4*>(dp);
            float4 y = *reinterpret_cast<const float4*>(dp + 4);
            uint4 u4;
            u4.x = pk2bf(x.x, x.y); u4.y = pk2bf(x.z, x.w);
            u4.z = pk2bf(y.x, y.y); u4.w = pk2bf(y.z, y.w);
            dreg[c2][ks] = __builtin_bit_cast(bf16x8, u4);
        }
    }

    // ---- build S (edge counts) in LDS region aliasing Ub ----
#pragma unroll
    for (int k = 0; k < 16; ++k) Sint[tid + k * 256] = 0;
    __syncthreads();
    {
        int4 pr = reinterpret_cast<const int4*>(pairs)[tid];   // pairs 2*tid, 2*tid+1
        atomicAdd(&Sint[(pr.x & (NL - 1)) * NL + (pr.y & (NL - 1))], 1);
        atomicAdd(&Sint[(pr.z & (NL - 1)) * NL + (pr.w & (NL - 1))], 1);
    }
    __syncthreads();
    float sreg[4][4];
#pragma unroll
    for (int nt = 0; nt < 4; ++nt)
#pragma unroll
        for (int r = 0; r < 4; ++r)
            sreg[nt][r] = (float)Sint[(16 * w + 4 * lg + r) * NL + nt * 16 + l15];
    __syncthreads();   // all S reads done before Ub is overwritten

    f32x4 m[4];

    for (int rep = 0; rep < reps; ++rep) {     // runtime bound: no unroll/dedup
        if (rep > 0) loadA(b0);                // re-fetch (L3-resident on reps>0)
        cvtStore(Ab0);
        __syncthreads();

#pragma unroll
        for (int nt = 0; nt < 4; ++nt) m[nt] = (f32x4)0.0f;

#pragma unroll
        for (int bb = 0; bb < BPB; ++bb) {
            ushort* Acur = (bb & 1) ? Ab1 : Ab0;
            ushort* Anxt = (bb & 1) ? Ab0 : Ab1;
            if (bb + 1 < BPB) loadA(b0 + bb + 1);   // prefetch under U+M compute

            // ---- U-step ----
            f32x4 u[4][2];
#pragma unroll
            for (int it = 0; it < 4; ++it) { u[it][0] = (f32x4)0.0f; u[it][1] = (f32x4)0.0f; }
#pragma unroll
            for (int ks = 0; ks < 4; ++ks) {
                const uint koff = (uint)(ks * 64 + lg * 16);
#pragma unroll
                for (int it = 0; it < 4; ++it) {
                    bf16x8 a = *reinterpret_cast<const bf16x8*>((const char*)Acur + (it * 16 + l15) * 256 + (koff ^ rmask));
                    u[it][0] = __builtin_amdgcn_mfma_f32_16x16x32_bf16(a, dreg[0][ks], u[it][0], 0, 0, 0);
                    u[it][1] = __builtin_amdgcn_mfma_f32_16x16x32_bf16(a, dreg[1][ks], u[it][1], 0, 0, 0);
                }
            }
            // ---- U frags -> Ub (scalar b16, swizzled) ----
#pragma unroll
            for (int it = 0; it < 4; ++it)
#pragma unroll
                for (int c2 = 0; c2 < 2; ++c2)
#pragma unroll
                    for (int r = 0; r < 4; ++r) {
                        const int  row = it * 16 + 4 * lg + r;
                        const uint cb  = (uint)((2 * w + c2) * 16 + l15) * 2;
                        *reinterpret_cast<ushort*>((char*)Ub + row * 256 + (cb ^ ((uint)(row & 15) << 4))) = f2bf(u[it][c2][r]);
                    }
            __syncthreads();   // bar1: full Ub visible

            // ---- M-step ----
#pragma unroll
            for (int ks = 0; ks < 4; ++ks) {
                const uint koff = (uint)(ks * 64 + lg * 16);
                bf16x8 a2 = *reinterpret_cast<const bf16x8*>((const char*)Ub + (16 * w + l15) * 256 + (koff ^ rmask));
#pragma unroll
                for (int nt = 0; nt < 4; ++nt) {
                    bf16x8 bfr = *reinterpret_cast<const bf16x8*>((const char*)Acur + (nt * 16 + l15) * 256 + (koff ^ rmask));
                    m[nt] = __builtin_amdgcn_mfma_f32_16x16x32_bf16(a2, bfr, m[nt], 0, 0, 0);
                }
            }
            if (bb + 1 < BPB) cvtStore(Anxt);
            __syncthreads();   // bar2: Anxt staged; Ub safe to rewrite next iter
        }
    }

    // ---- epilogue: <S, M> partial, block-reduce, plain store ----
    float s = 0.0f;
#pragma unroll
    for (int nt = 0; nt < 4; ++nt)
#pragma unroll
        for (int r = 0; r < 4; ++r) s = fmaf(m[nt][r], sreg[nt][r], s);
#pragma unroll
    for (int off = 32; off > 0; off >>= 1) s += __shfl_down(s, off, 64);

    if (lane == 0) wsum[w] = s;
    __syncthreads();
    if (tid == 0) partials[blockIdx.x] = wsum[0] + wsum[1] + wsum[2] + wsum[3];
}

// ---------------------------------------------------------------------------
// finish: reduce 512 partials, scale, write out[0]
// ---------------------------------------------------------------------------
__global__ void finish_kernel(const float* __restrict__ partials,
                              float* __restrict__ out) {
    __shared__ float wsum[4];
    const int tid = threadIdx.x, lane = tid & 63, w = tid >> 6;
    float2 v = reinterpret_cast<const float2*>(partials)[tid];   // 256*2 = 512
    float s = v.x + v.y;
#pragma unroll
    for (int off = 32; off > 0; off >>= 1) s += __shfl_down(s, off, 64);
    if (lane == 0) wsum[w] = s;
    __syncthreads();
    if (tid == 0)
        out[0] = (wsum[0] + wsum[1] + wsum[2] + wsum[3]) *
                 (1.0f / ((float)B_TOTAL * (float)NPAIRS));
}

extern "C" void kernel_launch(void* const* d_in, const int* in_sizes, int n_in,
                              void* d_out, int out_size, void* d_ws, size_t ws_size,
                              hipStream_t stream) {
    const float* P     = (const float*)d_in[0];
    const float* Dsrc  = (const float*)d_in[1];
    const int*   pairs = (const int*)d_in[2];
    float* out = (float*)d_out;

    float* partials = (float*)d_ws;   // 512 floats

    edge_loss_v6<<<NBLOCKS, 256, 0, stream>>>(P, Dsrc, pairs, partials, 2);
    finish_kernel<<<1, 256, 0, stream>>>(partials, out);
}

// Round 13
// 183.995 us; speedup vs baseline: 1.0690x; 1.0690x over previous
//
#include <hip/hip_runtime.h>
#include <hip/hip_bf16.h>

#define B_TOTAL 2048
#define H 128
#define NL 64
#define NPAIRS 512
#define BPB 4
#define NBLOCKS (B_TOTAL / BPB)   // 512

typedef __attribute__((ext_vector_type(8))) short bf16x8;  // MFMA A/B frag (8 bf16)
typedef __attribute__((ext_vector_type(4))) float f32x4;   // MFMA C/D frag

static __device__ __forceinline__ ushort f2bf(float f) {
    uint u = __float_as_uint(f);
    u += 0x7fffu + ((u >> 16) & 1u);   // RNE
    return (ushort)(u >> 16);
}
static __device__ __forceinline__ uint pk2bf(float x, float y) {
    return (uint)f2bf(x) | ((uint)f2bf(y) << 16);
}

// ---------------------------------------------------------------------------
// edge v5 (production): per block, build S in LDS (aliased into Ub region,
// consumed before first U-store), D-frags loaded straight from f32 global
// with in-register bf16 convert, then a 4-batch double-buffered pipeline:
//   loadA(b+1) || { U = A*D ; U->Ub ; M += U*A^T } ; cvtStore(b+1).
// D symmetric => both MFMA B-operands are natural row-major (no transposes).
// LDS swizzle: physical_byte = row*256 + (logical_col_byte ^ ((row&15)<<4)).
// Measured (R12 reps-probe): pipeline ~9.6us/pass, kernel ~15us total vs
// ~10.2us HBM floor; scored dur dominated by ~170us fixed harness work.
// ---------------------------------------------------------------------------
__global__ __launch_bounds__(256, 2)
void edge_loss_v5(const float* __restrict__ P,
                  const float* __restrict__ Dsrc,
                  const int* __restrict__ pairs,
                  float* __restrict__ partials) {
    __shared__ __align__(16) char lds_raw[49152];   // Ab0 | Ab1 | Ub  (16KB each)
    ushort* Ab0  = (ushort*)lds_raw;
    ushort* Ab1  = (ushort*)(lds_raw + 16384);
    ushort* Ub   = (ushort*)(lds_raw + 32768);
    int*    Sint = (int*)(lds_raw + 32768);         // aliases Ub (pre-U only)
    __shared__ float wsum[4];

    const int tid  = threadIdx.x;
    const int lane = tid & 63;
    const int w    = tid >> 6;            // wave 0..3
    const int l15  = lane & 15;
    const int lg   = lane >> 4;           // 0..3
    const uint rmask = (uint)l15 << 4;    // frag rows are tile*16+l15 -> row&15==l15
    const int b0   = blockIdx.x * BPB;

    float4 pf[8];
    auto loadA = [&](int b) {
        const float4* s = reinterpret_cast<const float4*>(P + (size_t)b * H * H);
#pragma unroll
        for (int k = 0; k < 8; ++k) pf[k] = s[tid + k * 256];
    };
    auto cvtStore = [&](ushort* dst) {
#pragma unroll
        for (int k = 0; k < 8; ++k) {
            const int  f4 = tid + k * 256;
            const int  i  = f4 >> 5;                // A row 0..63
            const uint cb = (uint)(f4 & 31) * 8;    // col byte 0..248
            uint2 d2;
            d2.x = pk2bf(pf[k].x, pf[k].y);
            d2.y = pk2bf(pf[k].z, pf[k].w);
            *reinterpret_cast<uint2*>((char*)dst + i * 256 + (cb ^ ((uint)(i & 15) << 4))) = d2;
        }
    };

    // ---- issue first batch's HBM loads immediately (hides under D/S setup) ----
    loadA(b0);

    // ---- D frags -> registers (f32 global, cvt in reg); wave w: rows [32w,32w+32) ----
    bf16x8 dreg[2][4];
#pragma unroll
    for (int c2 = 0; c2 < 2; ++c2) {
        const int drow = (2 * w + c2) * 16 + l15;
#pragma unroll
        for (int ks = 0; ks < 4; ++ks) {
            const float* dp = Dsrc + (size_t)drow * H + ks * 32 + lg * 8;
            float4 x = *reinterpret_cast<const float4*>(dp);
            float4 y = *reinterpret_cast<const float4*>(dp + 4);
            uint4 u4;
            u4.x = pk2bf(x.x, x.y); u4.y = pk2bf(x.z, x.w);
            u4.z = pk2bf(y.x, y.y); u4.w = pk2bf(y.z, y.w);
            dreg[c2][ks] = __builtin_bit_cast(bf16x8, u4);
        }
    }

    // ---- build S (edge counts) in LDS region aliasing Ub ----
#pragma unroll
    for (int k = 0; k < 16; ++k) Sint[tid + k * 256] = 0;
    __syncthreads();
    {
        int4 pr = reinterpret_cast<const int4*>(pairs)[tid];   // pairs 2*tid, 2*tid+1
        atomicAdd(&Sint[(pr.x & (NL - 1)) * NL + (pr.y & (NL - 1))], 1);
        atomicAdd(&Sint[(pr.z & (NL - 1)) * NL + (pr.w & (NL - 1))], 1);
    }
    __syncthreads();
    float sreg[4][4];
#pragma unroll
    for (int nt = 0; nt < 4; ++nt)
#pragma unroll
        for (int r = 0; r < 4; ++r)
            sreg[nt][r] = (float)Sint[(16 * w + 4 * lg + r) * NL + nt * 16 + l15];
    __syncthreads();   // all S reads done before Ub is overwritten

    // ---- stage batch 0 ----
    cvtStore(Ab0);
    __syncthreads();

    f32x4 m[4];
#pragma unroll
    for (int nt = 0; nt < 4; ++nt) m[nt] = (f32x4)0.0f;

#pragma unroll
    for (int bb = 0; bb < BPB; ++bb) {
        ushort* Acur = (bb & 1) ? Ab1 : Ab0;
        ushort* Anxt = (bb & 1) ? Ab0 : Ab1;
        if (bb + 1 < BPB) loadA(b0 + bb + 1);   // prefetch: hides under U+M compute

        // ---- U-step: u[it][c2] = A-rows it*16.. x D-rows (2w+c2)*16.. ----
        f32x4 u[4][2];
#pragma unroll
        for (int it = 0; it < 4; ++it) { u[it][0] = (f32x4)0.0f; u[it][1] = (f32x4)0.0f; }
#pragma unroll
        for (int ks = 0; ks < 4; ++ks) {
            const uint koff = (uint)(ks * 64 + lg * 16);
#pragma unroll
            for (int it = 0; it < 4; ++it) {
                bf16x8 a = *reinterpret_cast<const bf16x8*>((const char*)Acur + (it * 16 + l15) * 256 + (koff ^ rmask));
                u[it][0] = __builtin_amdgcn_mfma_f32_16x16x32_bf16(a, dreg[0][ks], u[it][0], 0, 0, 0);
                u[it][1] = __builtin_amdgcn_mfma_f32_16x16x32_bf16(a, dreg[1][ks], u[it][1], 0, 0, 0);
            }
        }
        // ---- U frags -> Ub (scalar b16, swizzled; conflict-free by construction) ----
#pragma unroll
        for (int it = 0; it < 4; ++it)
#pragma unroll
            for (int c2 = 0; c2 < 2; ++c2)
#pragma unroll
                for (int r = 0; r < 4; ++r) {
                    const int  row = it * 16 + 4 * lg + r;
                    const uint cb  = (uint)((2 * w + c2) * 16 + l15) * 2;
                    *reinterpret_cast<ushort*>((char*)Ub + row * 256 + (cb ^ ((uint)(row & 15) << 4))) = f2bf(u[it][c2][r]);
                }
        __syncthreads();   // bar1: full Ub visible

        // ---- M-step: wave w computes M rows [16w,16w+16), all 64 cols ----
#pragma unroll
        for (int ks = 0; ks < 4; ++ks) {
            const uint koff = (uint)(ks * 64 + lg * 16);
            bf16x8 a2 = *reinterpret_cast<const bf16x8*>((const char*)Ub + (16 * w + l15) * 256 + (koff ^ rmask));
#pragma unroll
            for (int nt = 0; nt < 4; ++nt) {
                bf16x8 bfr = *reinterpret_cast<const bf16x8*>((const char*)Acur + (nt * 16 + l15) * 256 + (koff ^ rmask));
                m[nt] = __builtin_amdgcn_mfma_f32_16x16x32_bf16(a2, bfr, m[nt], 0, 0, 0);
            }
        }
        if (bb + 1 < BPB) cvtStore(Anxt);
        __syncthreads();   // bar2: Anxt staged; Ub safe to rewrite next iter
    }

    // ---- epilogue: <S, M> partial, block-reduce, plain store ----
    float s = 0.0f;
#pragma unroll
    for (int nt = 0; nt < 4; ++nt)
#pragma unroll
        for (int r = 0; r < 4; ++r) s = fmaf(m[nt][r], sreg[nt][r], s);
#pragma unroll
    for (int off = 32; off > 0; off >>= 1) s += __shfl_down(s, off, 64);

    if (lane == 0) wsum[w] = s;
    __syncthreads();
    if (tid == 0) partials[blockIdx.x] = wsum[0] + wsum[1] + wsum[2] + wsum[3];
}

// ---------------------------------------------------------------------------
// finish: reduce 512 partials, scale, write out[0]
// ---------------------------------------------------------------------------
__global__ void finish_kernel(const float* __restrict__ partials,
                              float* __restrict__ out) {
    __shared__ float wsum[4];
    const int tid = threadIdx.x, lane = tid & 63, w = tid >> 6;
    float2 v = reinterpret_cast<const float2*>(partials)[tid];   // 256*2 = 512
    float s = v.x + v.y;
#pragma unroll
    for (int off = 32; off > 0; off >>= 1) s += __shfl_down(s, off, 64);
    if (lane == 0) wsum[w] = s;
    __syncthreads();
    if (tid == 0)
        out[0] = (wsum[0] + wsum[1] + wsum[2] + wsum[3]) *
                 (1.0f / ((float)B_TOTAL * (float)NPAIRS));
}

extern "C" void kernel_launch(void* const* d_in, const int* in_sizes, int n_in,
                              void* d_out, int out_size, void* d_ws, size_t ws_size,
                              hipStream_t stream) {
    const float* P     = (const float*)d_in[0];
    const float* Dsrc  = (const float*)d_in[1];
    const int*   pairs = (const int*)d_in[2];
    float* out = (float*)d_out;

    float* partials = (float*)d_ws;   // 512 floats

    edge_loss_v5<<<NBLOCKS, 256, 0, stream>>>(P, Dsrc, pairs, partials);
    finish_kernel<<<1, 256, 0, stream>>>(partials, out);
}